// Round 1
// baseline (134.185 us; speedup 1.0000x reference)
//
#include <hip/hip_runtime.h>
#include <hip/hip_fp16.h>

#define NQ   12
#define DIM  4096      // 2^NQ
#define NL   2
#define BATCH 4096

typedef float v2f __attribute__((ext_vector_type(2)));

// ---------------------------------------------------------------------------
// Changes vs previous round (42 us qc_sim, 4 blocks/CU, LDS-capped):
//  * Transpose buffer packed to __half2 (RN): LDS 35.3 KB -> 17.6 KB, so 8
//    blocks/CU resident (thread-capped), doubling latency-hiding waves.
//    Precision: two fp16 round-trips on |amp|<=~0.07 -> prob absmax ~1e-5;
//    build_gates upgraded to precise sincosf to offset.
//  * Carry-free LDS addressing: lds_off(map(r,t)) == A(t) + K(r) exactly
//    (verified: no carries cross the >>4 / >>10 boundaries for any map),
//    so per-r offsets are compile-time -> ds offset immediates + read2/write2
//    pairing, cutting per-access VALU address math.
//  * Skew is now i + (i>>4) + 9*(i>>10): old skew left idx bits{10,11}
//    (stride 1088 == 0 mod 32) unskewed -> map2 pattern was 4-way bank
//    conflicted; coeff 9 gives 16 distinct banks -> all patterns at the
//    free 2-way floor.
// Layouts (elem bits <- source), unchanged:
//   map1: {0,1}<-r0r1(e), {2..7}<-t0..t5, {8,9}<-t6t7(wave), {10,11}<-r2r3(j)
//   map2: {0,1}<-t0t1, {2,3}<-r0r1, {4,5}<-r2r3, {6,7}<-t2t3,
//         {8,9}<-t6t7(wave), {10,11}<-t4t5
//   map3: {0..5}<-t0..t5, {6..9}<-r, {10,11}<-t6t7   (coalesced stores)
// Gates per stage: s1: bits 0,1,10,11 ; s2: bits 2..5 ; s3: bits 6..9.
// Transpose 1 stays wave-local (wave bits t6,t7 pinned to idx bits {8,9} on
// both sides; per-wave in-order DS gives write->read ordering, no barrier).
// ---------------------------------------------------------------------------

struct PGate { v2f a00, b00, a01, b01, a10, b10, a11, b11; };

__global__ void build_gates(const float* __restrict__ th,
                            const float* __restrict__ ph,
                            const float* __restrict__ lm,
                            float* __restrict__ gates) {
    int q = threadIdx.x;
    if (q >= NQ) return;
    float g00r = 1.f, g00i = 0.f, g01r = 0.f, g01i = 0.f;
    float g10r = 0.f, g10i = 0.f, g11r = 1.f, g11i = 0.f;
    #pragma unroll
    for (int l = 0; l < NL; ++l) {
        float th2 = 0.5f * th[l * NQ + q];
        float p   = ph[l * NQ + q];
        float la  = lm[l * NQ + q];
        float s, c, sl, cl, sp, cp, spl, cpl;
        sincosf(th2, &s, &c);       // precise: this kernel is 12 threads, free
        sincosf(la, &sl, &cl);
        sincosf(p, &sp, &cp);
        sincosf(p + la, &spl, &cpl);
        float u00r = c,        u00i = 0.f;
        float u01r = -cl * s,  u01i = -sl * s;
        float u10r = cp * s,   u10i = sp * s;
        float u11r = cpl * c,  u11i = spl * c;
        float n00r = u00r*g00r - u00i*g00i + u01r*g10r - u01i*g10i;
        float n00i = u00r*g00i + u00i*g00r + u01r*g10i + u01i*g10r;
        float n01r = u00r*g01r - u00i*g01i + u01r*g11r - u01i*g11i;
        float n01i = u00r*g01i + u00i*g01r + u01r*g11i + u01i*g11r;
        float n10r = u10r*g00r - u10i*g00i + u11r*g10r - u11i*g10i;
        float n10i = u10r*g00i + u10i*g00r + u11r*g10i + u11i*g10r;
        float n11r = u10r*g01r - u10i*g01i + u11r*g11r - u11i*g11i;
        float n11i = u10r*g01i + u10i*g01r + u11r*g11i + u11i*g11r;
        g00r = n00r; g00i = n00i; g01r = n01r; g01i = n01i;
        g10r = n10r; g10i = n10i; g11r = n11r; g11i = n11i;
    }
    int k = (NQ - 1) - q;  // qubit 0 is the MSB of the state index
    float* o = gates + k * 16;
    o[0]  = g00r;  o[1]  = g00i;  o[2]  = -g00i; o[3]  = g00r;   // a00, b00
    o[4]  = g01r;  o[5]  = g01i;  o[6]  = -g01i; o[7]  = g01r;   // a01, b01
    o[8]  = g10r;  o[9]  = g10i;  o[10] = -g10i; o[11] = g10r;   // a10, b10
    o[12] = g11r;  o[13] = g11i;  o[14] = -g11i; o[15] = g11r;   // a11, b11
}

__device__ __forceinline__ v2f blo(v2f x) { return __builtin_shufflevector(x, x, 0, 0); }
__device__ __forceinline__ v2f bhi(v2f x) { return __builtin_shufflevector(x, x, 1, 1); }

__device__ __forceinline__ void papply(v2f v[16], int r0, int r1, const PGate& g) {
    v2f x0 = v[r0], x1 = v[r1];
    v2f x0r = blo(x0), x0i = bhi(x0), x1r = blo(x1), x1i = bhi(x1);
    v[r0] = g.a00 * x0r + g.b00 * x0i + g.a01 * x1r + g.b01 * x1i;
    v[r1] = g.a10 * x0r + g.b10 * x0i + g.a11 * x1r + g.b11 * x1i;
}

// apply gate on register-bit rb (pairs differ in bit rb of the 4-bit reg idx)
__device__ __forceinline__ void papply_rbit(v2f v[16], int rb, const PGate& g) {
    const int m = 1 << rb;
    #pragma unroll
    for (int h = 0; h < 8; ++h) {
        int low = h & (m - 1);
        int r   = ((h & ~(m - 1)) << 1) | low;   // insert 0 at bit rb
        papply(v, r, r | m, g);
    }
}

__device__ __forceinline__ __half2 pack2(v2f x) {
    return __floats2half2_rn(x.x, x.y);          // RN: half the RTZ error
}
__device__ __forceinline__ v2f unpack2(__half2 h) {
    return (v2f){ __low2float(h), __high2float(h) };
}

// max skewed index: 4095 + 255 + 27 = 4377
#define LDS_N 4384

__global__ __launch_bounds__(256, 8)
void qc_sim(const float* __restrict__ in,
            const PGate* __restrict__ gp,
            float* __restrict__ out) {
    __shared__ __half2 st[LDS_N];          // 17.1 KB packed transpose buffer
    __shared__ float red[4];               // per-wave sumsq

    const int t    = threadIdx.x;
    const int lane = t & 63;
    const int b    = blockIdx.x;

    // ---- issue global loads first (coalesced float4) ----
    const float4* __restrict__ x4 =
        reinterpret_cast<const float4*>(in + (size_t)b * DIM);
    float4 lA[4];
    #pragma unroll
    for (int j = 0; j < 4; ++j) lA[j] = x4[j * 256 + t];

    // ---- sum of squares, per-wave reduce ----
    float ss = 0.f;
    #pragma unroll
    for (int j = 0; j < 4; ++j)
        ss += lA[j].x*lA[j].x + lA[j].y*lA[j].y + lA[j].z*lA[j].z + lA[j].w*lA[j].w;
    #pragma unroll
    for (int off = 32; off > 0; off >>= 1)
        ss += __shfl_down(ss, off, 64);
    if (lane == 0) red[t >> 6] = ss;

    v2f v[16];

    // ---- stage 1 (gates 0,1,10,11), first gate fed from pure-real input ----
    {
        PGate g0 = gp[0];
        #pragma unroll
        for (int j = 0; j < 4; ++j) {
            v2f x0, x1;
            x0 = (v2f){ lA[j].x, lA[j].x }; x1 = (v2f){ lA[j].y, lA[j].y };
            v[4*j]   = g0.a00 * x0 + g0.a01 * x1;  v[4*j+1] = g0.a10 * x0 + g0.a11 * x1;
            x0 = (v2f){ lA[j].z, lA[j].z }; x1 = (v2f){ lA[j].w, lA[j].w };
            v[4*j+2] = g0.a00 * x0 + g0.a01 * x1;  v[4*j+3] = g0.a10 * x0 + g0.a11 * x1;
        }
        { PGate g = gp[1];  papply_rbit(v, 1, g); }
        { PGate g = gp[10]; papply_rbit(v, 2, g); }
        { PGate g = gp[11]; papply_rbit(v, 3, g); }
    }

    // Skewed bases: lds_off(i) = i + (i>>4) + 9*(i>>10), decomposed exactly
    // into per-thread base A + compile-time per-r K (no carries: verified
    // low-4 and low-10 sums never overflow for any map).
    const int A1 = (t << 2) + (t >> 2);                           // base of map1
    const int b2 = (t & 3) | (((t >> 2) & 3) << 6)
                 | (((t >> 6) & 3) << 8) | (((t >> 4) & 3) << 10);
    const int A2 = b2 + (b2 >> 4) + 9 * ((t >> 4) & 3);           // base of map2
    const int b3 = (t & 63) | ((t >> 6) << 10);
    const int A3 = b3 + (b3 >> 4) + 9 * (t >> 6);                 // base of map3

    // ---- transpose 1: WAVE-LOCAL (map1 -> map2), no block barrier ----
    #pragma unroll
    for (int r = 0; r < 16; ++r) {
        const int K1 = ((r >> 2) << 10) + ((r >> 2) << 6) + 9 * (r >> 2) + (r & 3);
        st[A1 + K1] = pack2(v[r]);
    }
    #pragma unroll
    for (int r = 0; r < 16; ++r) {
        const int K2 = ((r & 3) << 2) + ((r >> 2) << 4) + (r >> 2);
        v[r] = unpack2(st[A2 + K2]);
    }

    // ---- stage 2 (gates on idx bits 2..5) ----
    { PGate g = gp[2]; papply_rbit(v, 0, g); }
    { PGate g = gp[3]; papply_rbit(v, 1, g); }
    { PGate g = gp[4]; papply_rbit(v, 2, g); }
    { PGate g = gp[5]; papply_rbit(v, 3, g); }

    // ---- transpose 2: write back to own map2 slots (thread-private WAR),
    //      ONE barrier, cross-wave read at map3 ----
    #pragma unroll
    for (int r = 0; r < 16; ++r) {
        const int K2 = ((r & 3) << 2) + ((r >> 2) << 4) + (r >> 2);
        st[A2 + K2] = pack2(v[r]);
    }
    __syncthreads();
    #pragma unroll
    for (int r = 0; r < 16; ++r) v[r] = unpack2(st[A3 + 68 * r]);

    // ---- stage 3 (gates on idx bits 6..9) ----
    { PGate g = gp[6]; papply_rbit(v, 0, g); }
    { PGate g = gp[7]; papply_rbit(v, 1, g); }
    { PGate g = gp[8]; papply_rbit(v, 2, g); }
    { PGate g = gp[9]; papply_rbit(v, 3, g); }

    // ---- epilogue: prob = |state|^2 / ||x||^2, coalesced stores ----
    float inv = 1.0f / (red[0] + red[1] + red[2] + red[3]);
    float* __restrict__ o = out + (size_t)b * DIM;
    #pragma unroll
    for (int r = 0; r < 16; ++r) {
        v2f p2 = v[r] * v[r];
        o[b3 + (r << 6)] = (p2.x + p2.y) * inv;
    }
}

extern "C" void kernel_launch(void* const* d_in, const int* in_sizes, int n_in,
                              void* d_out, int out_size, void* d_ws, size_t ws_size,
                              hipStream_t stream) {
    (void)in_sizes; (void)n_in; (void)out_size; (void)ws_size;
    const float* inputs = (const float*)d_in[0];
    const float* thetas = (const float*)d_in[1];
    const float* phis   = (const float*)d_in[2];
    const float* lams   = (const float*)d_in[3];
    float* gates = (float*)d_ws;              // 192 floats of scratch
    float* out   = (float*)d_out;

    hipLaunchKernelGGL(build_gates, dim3(1), dim3(64), 0, stream,
                       thetas, phis, lams, gates);
    hipLaunchKernelGGL(qc_sim, dim3(BATCH), dim3(256), 0, stream,
                       inputs, (const PGate*)gates, out);
}

// Round 3
// 132.358 us; speedup vs baseline: 1.0138x; 1.0138x over previous
//
#include <hip/hip_runtime.h>
#include <hip/hip_fp16.h>

#define NQ   12
#define DIM  4096      // 2^NQ
#define NL   2
#define BATCH 4096

typedef float  v2f __attribute__((ext_vector_type(2)));
typedef __fp16 hv2 __attribute__((ext_vector_type(2)));

// ---------------------------------------------------------------------------
// Round-3 = round-2 with the cvt_pkrtz union typed as __fp16 vector (the
// builtin's actual return type on gfx950); everything else unchanged.
//
// Round-2 changes (prev: 42 us qc_sim, VALUBusy 62%, conflicts 2.1M after the
// 4B-element repack invalidated the additive skew):
//  * PROVEN conflict-free XOR layouts, one per transpose buffer use.
//    Bank bits need rank 5 over write-side lane bits AND read-side lane bits:
//      layout A (T1):  bank = (i2^i0, i3^i1, i4^i7, i5^i10, i6)
//                      upper = (i0, i1, i7, i10, i11, i8, i9)
//      layout B (T2):  bank = (i0, i1, i2^i6, i3^i7, i4^i10)
//                      upper = (i6, i7, i10, i5, i11, i8, i9)
//    All four access patterns hit 32 distinct banks per 32-lane phase -> 0
//    conflicts. Addressing: addr = base(lane) ^ K(r), K compile-time (bit
//    disjointness verified; numeric spot-check at idx 2918 on all 4 paths).
//  * cvt_pkrtz pack (1 instr vs 3 for RN): absmax pinned at 2^-16 through two
//    rounds -> precision headroom; RTZ worst case ~2x RN, still ~1e-5 scale.
//  * ONE 16 KB buffer for both transposes: both layouts place the WRITER's
//    wave bits at slot{10,11}, so each wave's T2 writes land only in its own
//    already-consumed T1 region -> no extra barrier (still exactly one).
//  * Transpose writes interleaved into the last gate of each stage (write a
//    pair right after gp[11]/gp[5] produces it) to shorten the DS burst that
//    phase-aligns across waves.
// Gates per stage unchanged: s1: idx bits 0,1,10,11 ; s2: 2..5 ; s3: 6..9.
// T1 stays wave-local (idx{8,9}=t6t7 both sides; per-wave in-order DS).
// ---------------------------------------------------------------------------

struct PGate { v2f a00, b00, a01, b01, a10, b10, a11, b11; };

__global__ void build_gates(const float* __restrict__ th,
                            const float* __restrict__ ph,
                            const float* __restrict__ lm,
                            float* __restrict__ gates) {
    int q = threadIdx.x;
    if (q >= NQ) return;
    float g00r = 1.f, g00i = 0.f, g01r = 0.f, g01i = 0.f;
    float g10r = 0.f, g10i = 0.f, g11r = 1.f, g11i = 0.f;
    #pragma unroll
    for (int l = 0; l < NL; ++l) {
        float th2 = 0.5f * th[l * NQ + q];
        float p   = ph[l * NQ + q];
        float la  = lm[l * NQ + q];
        float s, c, sl, cl, sp, cp, spl, cpl;
        sincosf(th2, &s, &c);
        sincosf(la, &sl, &cl);
        sincosf(p, &sp, &cp);
        sincosf(p + la, &spl, &cpl);
        float u00r = c,        u00i = 0.f;
        float u01r = -cl * s,  u01i = -sl * s;
        float u10r = cp * s,   u10i = sp * s;
        float u11r = cpl * c,  u11i = spl * c;
        float n00r = u00r*g00r - u00i*g00i + u01r*g10r - u01i*g10i;
        float n00i = u00r*g00i + u00i*g00r + u01r*g10i + u01i*g10r;
        float n01r = u00r*g01r - u00i*g01i + u01r*g11r - u01i*g11i;
        float n01i = u00r*g01i + u00i*g01r + u01r*g11i + u01i*g11r;
        float n10r = u10r*g00r - u10i*g00i + u11r*g10r - u11i*g10i;
        float n10i = u10r*g00i + u10i*g00r + u11r*g10i + u11i*g10r;
        float n11r = u10r*g01r - u10i*g01i + u11r*g11r - u11i*g11i;
        float n11i = u10r*g01i + u10i*g01r + u11r*g11i + u11i*g11r;
        g00r = n00r; g00i = n00i; g01r = n01r; g01i = n01i;
        g10r = n10r; g10i = n10i; g11r = n11r; g11i = n11i;
    }
    int k = (NQ - 1) - q;  // qubit 0 is the MSB of the state index
    float* o = gates + k * 16;
    o[0]  = g00r;  o[1]  = g00i;  o[2]  = -g00i; o[3]  = g00r;   // a00, b00
    o[4]  = g01r;  o[5]  = g01i;  o[6]  = -g01i; o[7]  = g01r;   // a01, b01
    o[8]  = g10r;  o[9]  = g10i;  o[10] = -g10i; o[11] = g10r;   // a10, b10
    o[12] = g11r;  o[13] = g11i;  o[14] = -g11i; o[15] = g11r;   // a11, b11
}

__device__ __forceinline__ v2f blo(v2f x) { return __builtin_shufflevector(x, x, 0, 0); }
__device__ __forceinline__ v2f bhi(v2f x) { return __builtin_shufflevector(x, x, 1, 1); }

__device__ __forceinline__ void papply(v2f v[16], int r0, int r1, const PGate& g) {
    v2f x0 = v[r0], x1 = v[r1];
    v2f x0r = blo(x0), x0i = bhi(x0), x1r = blo(x1), x1i = bhi(x1);
    v[r0] = g.a00 * x0r + g.b00 * x0i + g.a01 * x1r + g.b01 * x1i;
    v[r1] = g.a10 * x0r + g.b10 * x0i + g.a11 * x1r + g.b11 * x1i;
}

// apply gate on register-bit rb (pairs differ in bit rb of the 4-bit reg idx)
__device__ __forceinline__ void papply_rbit(v2f v[16], int rb, const PGate& g) {
    const int m = 1 << rb;
    #pragma unroll
    for (int h = 0; h < 8; ++h) {
        int low = h & (m - 1);
        int r   = ((h & ~(m - 1)) << 1) | low;   // insert 0 at bit rb
        papply(v, r, r | m, g);
    }
}

__device__ __forceinline__ unsigned packrtz(v2f x) {
    union { hv2 h; unsigned u; } c;
    c.h = __builtin_amdgcn_cvt_pkrtz(x.x, x.y);   // single v_cvt_pkrtz_f16_f32
    return c.u;
}
__device__ __forceinline__ v2f unpackh(unsigned u) {
    union { unsigned u; hv2 h; } c; c.u = u;
    return (v2f){ (float)c.h.x, (float)c.h.y };
}

// Compile-time XOR keys (r = register index 0..15); see layout comment above.
// T1 write  (map1: i0,i1 <- r&3, i10,i11 <- r>>2):
#define K1W(r) ( (((r)&1)*33) + ((((r)>>1)&1)*66) + ((((r)>>2)&1)*264) + ((((r)>>3)&1)*512) )
// T1 read / T2 reg mapping (map2: i2..i5 <- r):
#define K1R(r) (r)
#define K2W(r) ( ((((r)&1))<<2) | (((((r)>>1)&1))<<3) | (((((r)>>2)&1))<<4) | (((((r)>>3)&1))<<8) )
// T2 read (map3: i6..i9 <- r):
#define K3R(r) ( (((r)&1)*36) + ((((r)>>1)&1)*72) + ((((r)>>2)&1)*1024) + ((((r)>>3)&1)*2048) )

__global__ __launch_bounds__(256, 8)
void qc_sim(const float* __restrict__ in,
            const PGate* __restrict__ gp,
            float* __restrict__ out) {
    __shared__ unsigned st[DIM];           // 16 KB packed transpose buffer
    __shared__ float red[4];               // per-wave sumsq

    const int t    = threadIdx.x;
    const int lane = t & 63;
    const int b    = blockIdx.x;

    // ---- issue global loads first (coalesced float4) ----
    const float4* __restrict__ x4 =
        reinterpret_cast<const float4*>(in + (size_t)b * DIM);
    float4 lA[4];
    #pragma unroll
    for (int j = 0; j < 4; ++j) lA[j] = x4[j * 256 + t];

    // ---- sum of squares, per-wave reduce ----
    float ss = 0.f;
    #pragma unroll
    for (int j = 0; j < 4; ++j)
        ss += lA[j].x*lA[j].x + lA[j].y*lA[j].y + lA[j].z*lA[j].z + lA[j].w*lA[j].w;
    #pragma unroll
    for (int off = 32; off > 0; off >>= 1)
        ss += __shfl_down(ss, off, 64);
    if (lane == 0) red[t >> 6] = ss;

    // ---- per-thread LDS base addresses (slot units, 4 B each) ----
    const int L0 = lane & 1, L1 = (lane >> 1) & 1, L2 = (lane >> 2) & 1,
              L3 = (lane >> 3) & 1, L4 = (lane >> 4) & 1, L5 = lane >> 5;
    const int w  = t >> 6, w0 = w & 1, w1 = w >> 1;
    // T1 write base: lanes are idx{2..7}; banks (L0^ra, L1^rb, L2^L5, L3^rc, L4)
    const int A1w = L0 | (L1 << 1) | ((L2 ^ L5) << 2) | (L3 << 3) | (L4 << 4)
                  | (L5 << 7) | (w << 10);
    // T1 read base: lanes are idx{0,1,6,7,10,11}
    const int A1r = L0 | (L1 << 1) | (L3 << 2) | (L4 << 3) | (L2 << 4)
                  | (L0 << 5) | (L1 << 6) | (L3 << 7) | (L4 << 8) | (L5 << 9)
                  | (w << 10);
    // T2 write base: lanes are idx{0,1,6,7,10,11} (map2 thread bits)
    const int A2w = L0 | (L1 << 1) | (L2 << 2) | (L3 << 3) | (L4 << 4)
                  | (L2 << 5) | (L3 << 6) | (L4 << 7) | (L5 << 9) | (w << 10);
    // T2 read base: lanes are idx{0..5}, wave bits i10,i11 = w
    const int A3  = L0 | (L1 << 1) | (L2 << 2) | (L3 << 3) | ((L4 ^ w0) << 4)
                  | (w0 << 7) | (L5 << 8) | (w1 << 9);

    v2f v[16];

    // ---- stage 1 (gates 0,1,10,11), first gate fed from pure-real input ----
    {
        PGate g0 = gp[0];
        #pragma unroll
        for (int j = 0; j < 4; ++j) {
            v2f x0, x1;
            x0 = (v2f){ lA[j].x, lA[j].x }; x1 = (v2f){ lA[j].y, lA[j].y };
            v[4*j]   = g0.a00 * x0 + g0.a01 * x1;  v[4*j+1] = g0.a10 * x0 + g0.a11 * x1;
            x0 = (v2f){ lA[j].z, lA[j].z }; x1 = (v2f){ lA[j].w, lA[j].w };
            v[4*j+2] = g0.a00 * x0 + g0.a01 * x1;  v[4*j+3] = g0.a10 * x0 + g0.a11 * x1;
        }
        { PGate g = gp[1];  papply_rbit(v, 1, g); }
        { PGate g = gp[10]; papply_rbit(v, 2, g); }
        // last stage-1 gate (reg bit 3): write each finished pair immediately
        { PGate g = gp[11];
          #pragma unroll
          for (int h = 0; h < 8; ++h) {
              papply(v, h, h | 8, g);
              st[A1w ^ K1W(h)]     = packrtz(v[h]);
              st[A1w ^ K1W(h | 8)] = packrtz(v[h | 8]);
          }
        }
    }

    // ---- transpose 1 read: WAVE-LOCAL, no block barrier ----
    #pragma unroll
    for (int r = 0; r < 16; ++r) v[r] = unpackh(st[A1r ^ K1R(r)]);

    // ---- stage 2 (gates on idx bits 2..5) ----
    { PGate g = gp[2]; papply_rbit(v, 0, g); }
    { PGate g = gp[3]; papply_rbit(v, 1, g); }
    { PGate g = gp[4]; papply_rbit(v, 2, g); }
    // last stage-2 gate (reg bit 3): interleave T2 writes with compute
    { PGate g = gp[5];
      #pragma unroll
      for (int h = 0; h < 8; ++h) {
          papply(v, h, h | 8, g);
          st[A2w ^ K2W(h)]     = packrtz(v[h]);
          st[A2w ^ K2W(h | 8)] = packrtz(v[h | 8]);
      }
    }

    __syncthreads();   // the one block barrier (cross-wave read follows)

    #pragma unroll
    for (int r = 0; r < 16; ++r) v[r] = unpackh(st[A3 ^ K3R(r)]);

    // ---- stage 3 (gates on idx bits 6..9) ----
    { PGate g = gp[6]; papply_rbit(v, 0, g); }
    { PGate g = gp[7]; papply_rbit(v, 1, g); }
    { PGate g = gp[8]; papply_rbit(v, 2, g); }
    { PGate g = gp[9]; papply_rbit(v, 3, g); }

    // ---- epilogue: prob = |state|^2 / ||x||^2, coalesced stores ----
    float inv = 1.0f / (red[0] + red[1] + red[2] + red[3]);
    const int sbase = lane | (w << 10);    // map3: idx{0..5}=t0..5, {10,11}=wave
    float* __restrict__ o = out + (size_t)b * DIM;
    #pragma unroll
    for (int r = 0; r < 16; ++r) {
        v2f p2 = v[r] * v[r];
        o[sbase + (r << 6)] = (p2.x + p2.y) * inv;
    }
}

extern "C" void kernel_launch(void* const* d_in, const int* in_sizes, int n_in,
                              void* d_out, int out_size, void* d_ws, size_t ws_size,
                              hipStream_t stream) {
    (void)in_sizes; (void)n_in; (void)out_size; (void)ws_size;
    const float* inputs = (const float*)d_in[0];
    const float* thetas = (const float*)d_in[1];
    const float* phis   = (const float*)d_in[2];
    const float* lams   = (const float*)d_in[3];
    float* gates = (float*)d_ws;              // 192 floats of scratch
    float* out   = (float*)d_out;

    hipLaunchKernelGGL(build_gates, dim3(1), dim3(64), 0, stream,
                       thetas, phis, lams, gates);
    hipLaunchKernelGGL(qc_sim, dim3(BATCH), dim3(256), 0, stream,
                       inputs, (const PGate*)gates, out);
}

// Round 4
// 128.389 us; speedup vs baseline: 1.0451x; 1.0309x over previous
//
#include <hip/hip_runtime.h>
#include <hip/hip_fp16.h>

#define NQ   12
#define DIM  4096      // 2^NQ
#define NL   2
#define BATCH 4096

typedef float  v2f __attribute__((ext_vector_type(2)));
typedef __fp16 hv2 __attribute__((ext_vector_type(2)));

// ---------------------------------------------------------------------------
// Round-4: FULL PACKED-FP16 AMPLITUDE PIPELINE.
// Round-3 post-mortem: conflicts 2.1M -> 0 as designed, but dur 42 -> 44.5 us.
// The kernel is f32-VALU-bound: v_pk_fma_f32 = 4 cyc/wave (SIMD-32, 2 f32
// FMA/lane); 768 pk instrs = 3072 cyc/wave = 20.5 us math floor per SIMD.
// Fix: amplitudes as __half2 (re,im); complex FMA = 2x __hfma2 with op_sel
// broadcast/swap (v_pk_fma_f16 = 2 cyc/wave) -> math floor 10.2 us. The
// transpose pack/unpack (96 instrs) vanishes: LDS element is already the
// packed 32-bit amp. Round-3's PROVEN conflict-free XOR layouts unchanged:
//   layout A (T1): bank=(i2^i0, i3^i1, i4^i7, i5^i10, i6)
//   layout B (T2): bank=(i0, i1, i2^i6, i3^i7, i4^i10)
// Epilogue: cvt both halves to f32, square+scale in f32.
// Gates stored as fp16 pairs per entry: g1=(gr,gi), g2=(-gi,gi) so
//   y = g (x) x  ==  hfma2(low2(g1), x, hfma2(g2, swap(x), acc-chain)).
// Precision: ~12 stages of fp16 RN roundings; predicted absmax 1-2.5e-4
// (was 3e-5 from 2 roundings). Fallback if threshold fails: f32 stage 3.
// Gates per stage: s1: idx bits 0,1,10,11 ; s2: 2..5 ; s3: 6..9.
// T1 wave-local (idx{8,9}=t6t7 both sides); ONE block barrier total.
// ---------------------------------------------------------------------------

struct HGate { __half2 m[8]; };  // e00.g1,e00.g2, e01.g1,e01.g2, e10..., e11...

__global__ void build_gates(const float* __restrict__ th,
                            const float* __restrict__ ph,
                            const float* __restrict__ lm,
                            float* __restrict__ gates) {
    int q = threadIdx.x;
    if (q >= NQ) return;
    float g00r = 1.f, g00i = 0.f, g01r = 0.f, g01i = 0.f;
    float g10r = 0.f, g10i = 0.f, g11r = 1.f, g11i = 0.f;
    #pragma unroll
    for (int l = 0; l < NL; ++l) {
        float th2 = 0.5f * th[l * NQ + q];
        float p   = ph[l * NQ + q];
        float la  = lm[l * NQ + q];
        float s, c, sl, cl, sp, cp, spl, cpl;
        sincosf(th2, &s, &c);
        sincosf(la, &sl, &cl);
        sincosf(p, &sp, &cp);
        sincosf(p + la, &spl, &cpl);
        float u00r = c,        u00i = 0.f;
        float u01r = -cl * s,  u01i = -sl * s;
        float u10r = cp * s,   u10i = sp * s;
        float u11r = cpl * c,  u11i = spl * c;
        float n00r = u00r*g00r - u00i*g00i + u01r*g10r - u01i*g10i;
        float n00i = u00r*g00i + u00i*g00r + u01r*g10i + u01i*g10r;
        float n01r = u00r*g01r - u00i*g01i + u01r*g11r - u01i*g11i;
        float n01i = u00r*g01i + u00i*g01r + u01r*g11i + u01i*g11r;
        float n10r = u10r*g00r - u10i*g00i + u11r*g10r - u11i*g10i;
        float n10i = u10r*g00i + u10i*g00r + u11r*g10i + u11i*g10r;
        float n11r = u10r*g01r - u10i*g01i + u11r*g11r - u11i*g11i;
        float n11i = u10r*g01i + u10i*g01r + u11r*g11i + u11i*g11r;
        g00r = n00r; g00i = n00i; g01r = n01r; g01i = n01i;
        g10r = n10r; g10i = n10i; g11r = n11r; g11i = n11i;
    }
    int k = (NQ - 1) - q;  // qubit 0 is the MSB of the state index
    __half2* o = reinterpret_cast<__half2*>(gates) + (size_t)k * 8;
    o[0] = __floats2half2_rn(g00r,  g00i);
    o[1] = __floats2half2_rn(-g00i, g00i);
    o[2] = __floats2half2_rn(g01r,  g01i);
    o[3] = __floats2half2_rn(-g01i, g01i);
    o[4] = __floats2half2_rn(g10r,  g10i);
    o[5] = __floats2half2_rn(-g10i, g10i);
    o[6] = __floats2half2_rn(g11r,  g11i);
    o[7] = __floats2half2_rn(-g11i, g11i);
}

__device__ __forceinline__ unsigned h2u(__half2 x) {
    union { __half2 h; unsigned u; } c; c.h = x; return c.u;
}
__device__ __forceinline__ __half2 u2h(unsigned x) {
    union { unsigned u; __half2 h; } c; c.u = x; return c.h;
}
__device__ __forceinline__ __half2 rbroad(float x) {   // (x,x) -> fp16, 1 instr
    union { hv2 a; __half2 b; } c;
    c.a = __builtin_amdgcn_cvt_pkrtz(x, x);
    return c.b;
}

// acc += g (x) x   (complex):  2x v_pk_fma_f16, op_sel folds broadcast/swap
__device__ __forceinline__ __half2 cfma(__half2 g1, __half2 g2, __half2 x,
                                        __half2 acc) {
    acc = __hfma2(__low2half2(g1), x, acc);
    acc = __hfma2(g2, __lowhigh2highlow(x), acc);
    return acc;
}

__device__ __forceinline__ void papply(__half2 v[16], int r0, int r1,
                                       const HGate& g) {
    __half2 x0 = v[r0], x1 = v[r1];
    __half2 a = __hmul2(__low2half2(g.m[2]), x1);          // e01.r * x1
    a = __hfma2(g.m[3], __lowhigh2highlow(x1), a);
    a = cfma(g.m[0], g.m[1], x0, a);
    __half2 b = __hmul2(__low2half2(g.m[6]), x1);          // e11.r * x1
    b = __hfma2(g.m[7], __lowhigh2highlow(x1), b);
    b = cfma(g.m[4], g.m[5], x0, b);
    v[r0] = a; v[r1] = b;
}

// apply gate on register-bit rb (pairs differ in bit rb of the 4-bit reg idx)
__device__ __forceinline__ void papply_rbit(__half2 v[16], int rb,
                                            const HGate& g) {
    const int m = 1 << rb;
    #pragma unroll
    for (int h = 0; h < 8; ++h) {
        int low = h & (m - 1);
        int r   = ((h & ~(m - 1)) << 1) | low;   // insert 0 at bit rb
        papply(v, r, r | m, g);
    }
}

// Compile-time XOR keys (r = register index 0..15); see layout comment above.
// T1 write  (map1: i0,i1 <- r&3, i10,i11 <- r>>2):
#define K1W(r) ( (((r)&1)*33) + ((((r)>>1)&1)*66) + ((((r)>>2)&1)*264) + ((((r)>>3)&1)*512) )
// T1 read / T2 reg mapping (map2: i2..i5 <- r):
#define K1R(r) (r)
#define K2W(r) ( ((((r)&1))<<2) | (((((r)>>1)&1))<<3) | (((((r)>>2)&1))<<4) | (((((r)>>3)&1))<<8) )
// T2 read (map3: i6..i9 <- r):
#define K3R(r) ( (((r)&1)*36) + ((((r)>>1)&1)*72) + ((((r)>>2)&1)*1024) + ((((r)>>3)&1)*2048) )

__global__ __launch_bounds__(256, 8)
void qc_sim(const float* __restrict__ in,
            const HGate* __restrict__ gp,
            float* __restrict__ out) {
    __shared__ unsigned st[DIM];           // 16 KB packed transpose buffer
    __shared__ float red[4];               // per-wave sumsq

    const int t    = threadIdx.x;
    const int lane = t & 63;
    const int b    = blockIdx.x;

    // ---- issue global loads first (coalesced float4) ----
    const float4* __restrict__ x4 =
        reinterpret_cast<const float4*>(in + (size_t)b * DIM);
    float4 lA[4];
    #pragma unroll
    for (int j = 0; j < 4; ++j) lA[j] = x4[j * 256 + t];

    // ---- sum of squares, per-wave reduce (exact, in f32) ----
    float ss = 0.f;
    #pragma unroll
    for (int j = 0; j < 4; ++j)
        ss += lA[j].x*lA[j].x + lA[j].y*lA[j].y + lA[j].z*lA[j].z + lA[j].w*lA[j].w;
    #pragma unroll
    for (int off = 32; off > 0; off >>= 1)
        ss += __shfl_down(ss, off, 64);
    if (lane == 0) red[t >> 6] = ss;

    // ---- per-thread LDS base addresses (slot units, 4 B each) ----
    const int L0 = lane & 1, L1 = (lane >> 1) & 1, L2 = (lane >> 2) & 1,
              L3 = (lane >> 3) & 1, L4 = (lane >> 4) & 1, L5 = lane >> 5;
    const int w  = t >> 6, w0 = w & 1, w1 = w >> 1;
    const int A1w = L0 | (L1 << 1) | ((L2 ^ L5) << 2) | (L3 << 3) | (L4 << 4)
                  | (L5 << 7) | (w << 10);
    const int A1r = L0 | (L1 << 1) | (L3 << 2) | (L4 << 3) | (L2 << 4)
                  | (L0 << 5) | (L1 << 6) | (L3 << 7) | (L4 << 8) | (L5 << 9)
                  | (w << 10);
    const int A2w = L0 | (L1 << 1) | (L2 << 2) | (L3 << 3) | (L4 << 4)
                  | (L2 << 5) | (L3 << 6) | (L4 << 7) | (L5 << 9) | (w << 10);
    const int A3  = L0 | (L1 << 1) | (L2 << 2) | (L3 << 3) | ((L4 ^ w0) << 4)
                  | (w0 << 7) | (L5 << 8) | (w1 << 9);

    __half2 v[16];

    // ---- stage 1 (gates 0,1,10,11); first gate fed from pure-real input ----
    {
        HGate g0 = gp[0];
        #pragma unroll
        for (int j = 0; j < 4; ++j) {
            __half2 xx0 = rbroad(lA[j].x), xx1 = rbroad(lA[j].y);
            v[4*j]   = __hfma2(g0.m[2], xx1, __hmul2(g0.m[0], xx0));
            v[4*j+1] = __hfma2(g0.m[6], xx1, __hmul2(g0.m[4], xx0));
            xx0 = rbroad(lA[j].z); xx1 = rbroad(lA[j].w);
            v[4*j+2] = __hfma2(g0.m[2], xx1, __hmul2(g0.m[0], xx0));
            v[4*j+3] = __hfma2(g0.m[6], xx1, __hmul2(g0.m[4], xx0));
        }
        { HGate g = gp[1];  papply_rbit(v, 1, g); }
        { HGate g = gp[10]; papply_rbit(v, 2, g); }
        // last stage-1 gate (reg bit 3): write each finished pair immediately
        { HGate g = gp[11];
          #pragma unroll
          for (int h = 0; h < 8; ++h) {
              papply(v, h, h | 8, g);
              st[A1w ^ K1W(h)]     = h2u(v[h]);
              st[A1w ^ K1W(h | 8)] = h2u(v[h | 8]);
          }
        }
    }

    // ---- transpose 1 read: WAVE-LOCAL, no block barrier ----
    #pragma unroll
    for (int r = 0; r < 16; ++r) v[r] = u2h(st[A1r ^ K1R(r)]);

    // ---- stage 2 (gates on idx bits 2..5) ----
    { HGate g = gp[2]; papply_rbit(v, 0, g); }
    { HGate g = gp[3]; papply_rbit(v, 1, g); }
    { HGate g = gp[4]; papply_rbit(v, 2, g); }
    // last stage-2 gate (reg bit 3): interleave T2 writes with compute
    { HGate g = gp[5];
      #pragma unroll
      for (int h = 0; h < 8; ++h) {
          papply(v, h, h | 8, g);
          st[A2w ^ K2W(h)]     = h2u(v[h]);
          st[A2w ^ K2W(h | 8)] = h2u(v[h | 8]);
      }
    }

    __syncthreads();   // the one block barrier (cross-wave read follows)

    #pragma unroll
    for (int r = 0; r < 16; ++r) v[r] = u2h(st[A3 ^ K3R(r)]);

    // ---- stage 3 (gates on idx bits 6..9) ----
    { HGate g = gp[6]; papply_rbit(v, 0, g); }
    { HGate g = gp[7]; papply_rbit(v, 1, g); }
    { HGate g = gp[8]; papply_rbit(v, 2, g); }
    { HGate g = gp[9]; papply_rbit(v, 3, g); }

    // ---- epilogue: prob = |state|^2 / ||x||^2 in f32, coalesced stores ----
    float inv = 1.0f / (red[0] + red[1] + red[2] + red[3]);
    const int sbase = lane | (w << 10);    // map3: idx{0..5}=t0..5, {10,11}=wave
    float* __restrict__ o = out + (size_t)b * DIM;
    #pragma unroll
    for (int r = 0; r < 16; ++r) {
        float re = __low2float(v[r]), im = __high2float(v[r]);
        o[sbase + (r << 6)] = (re * re + im * im) * inv;
    }
}

extern "C" void kernel_launch(void* const* d_in, const int* in_sizes, int n_in,
                              void* d_out, int out_size, void* d_ws, size_t ws_size,
                              hipStream_t stream) {
    (void)in_sizes; (void)n_in; (void)out_size; (void)ws_size;
    const float* inputs = (const float*)d_in[0];
    const float* thetas = (const float*)d_in[1];
    const float* phis   = (const float*)d_in[2];
    const float* lams   = (const float*)d_in[3];
    float* gates = (float*)d_ws;              // 96 B of scratch (12 x 8 half2)
    float* out   = (float*)d_out;

    hipLaunchKernelGGL(build_gates, dim3(1), dim3(64), 0, stream,
                       thetas, phis, lams, gates);
    hipLaunchKernelGGL(qc_sim, dim3(BATCH), dim3(256), 0, stream,
                       inputs, (const HGate*)gates, out);
}

// Round 5
// 128.077 us; speedup vs baseline: 1.0477x; 1.0024x over previous
//
#include <hip/hip_runtime.h>
#include <hip/hip_fp16.h>

#define NQ   12
#define DIM  4096      // 2^NQ
#define NL   2
#define BATCH 4096

typedef float  v2f __attribute__((ext_vector_type(2)));
typedef __fp16 hv2 __attribute__((ext_vector_type(2)));

// ---------------------------------------------------------------------------
// Round-5: TWO SAMPLES PER BLOCK, b64 LDS TRANSPOSES.
// Round-4 post-mortem: fp16 math halved VALU but qc_sim only 44.5->~40 us:
// kernel is issue/latency-bound; DS (64 b32 ops/thread @ ~5.8cyc) is the
// biggest non-math block. Fix: pack amp[idx] of samples (2b,2b+1) into one
// 8-B LDS element -> ds_*_b64 halves DS instrs/amp, amortizes addressing,
// barrier, and gate loads, and doubles in-wave ILP (two independent chains).
// LDS 16->32.8KB (4 blocks/CU = 16 waves/CU ~= measured ~18 anyway).
//
// Conflict-free layouts re-derived for 8-B elements (bank-pair = elem mod 16,
// 16-lane phases, t0..t3 varying within a phase):
//  layout A (T1): elem = (i2^i0)|(i3^i1)<<1|(i4^i6)<<2|(i5^i7)<<3
//                      | i0<<4|i1<<5|i6<<6|i7<<7|i8<<8|i9<<9|i10<<10|i11<<11
//    write (map1: i0,i1=r0,r1; i2..7=t0..5; i8,9=w; i10,11=r2,r3):
//      phase low4 = (t0^r0, t1^r1, t2^t4, t3^t5) -> rank 4 over t0..t3 OK
//    read  (map2: i0,1=t0,1; i2,3=r0,1; i4,5=r2,3; i6,7=t2,3; i8,9=w;
//           i10,11=t4,5): phase low4 = (r0^t0, r1^t1, r2^t2, r3^t3) OK
//  layout B (T2): elem = i0|i1<<1|(i2^i6)<<2|(i3^i7)<<3
//                      | i4<<4|i5<<5|i6<<6|i7<<7|i8<<8|i9<<9|i10<<10|i11<<11
//    write (map2): phase low4 = (t0, t1, r0^t2, r1^t3) OK
//    read  (map3: i0..5=t0..5; i6..9=r; i10,11=w):
//      phase low4 = (t0, t1, t2^r0, t3^r1) OK
//  Wave bits i8,i9 sit at elem bits 8,9 in BOTH layouts -> T1 wave-local
//  (no barrier) and T2 writes clobber only the writer's own consumed T1
//  region -> still exactly ONE __syncthreads.
// Addressing: elem = A(t) ^ K(r), K compile-time, key bits either XOR-design
// bits (0..3) or zero in the base (verified per-bit in the derivation).
// Gates per stage: s1: idx bits 0,1,10,11 ; s2: 2..5 ; s3: 6..9.
// ---------------------------------------------------------------------------

struct HGate { __half2 m[8]; };  // e00.g1,e00.g2, e01.g1,e01.g2, e10..., e11...

__global__ void build_gates(const float* __restrict__ th,
                            const float* __restrict__ ph,
                            const float* __restrict__ lm,
                            float* __restrict__ gates) {
    int q = threadIdx.x;
    if (q >= NQ) return;
    float g00r = 1.f, g00i = 0.f, g01r = 0.f, g01i = 0.f;
    float g10r = 0.f, g10i = 0.f, g11r = 1.f, g11i = 0.f;
    #pragma unroll
    for (int l = 0; l < NL; ++l) {
        float th2 = 0.5f * th[l * NQ + q];
        float p   = ph[l * NQ + q];
        float la  = lm[l * NQ + q];
        float s, c, sl, cl, sp, cp, spl, cpl;
        sincosf(th2, &s, &c);
        sincosf(la, &sl, &cl);
        sincosf(p, &sp, &cp);
        sincosf(p + la, &spl, &cpl);
        float u00r = c,        u00i = 0.f;
        float u01r = -cl * s,  u01i = -sl * s;
        float u10r = cp * s,   u10i = sp * s;
        float u11r = cpl * c,  u11i = spl * c;
        float n00r = u00r*g00r - u00i*g00i + u01r*g10r - u01i*g10i;
        float n00i = u00r*g00i + u00i*g00r + u01r*g10i + u01i*g10r;
        float n01r = u00r*g01r - u00i*g01i + u01r*g11r - u01i*g11i;
        float n01i = u00r*g01i + u00i*g01r + u01r*g11i + u01i*g11r;
        float n10r = u10r*g00r - u10i*g00i + u11r*g10r - u11i*g10i;
        float n10i = u10r*g00i + u10i*g00r + u11r*g10i + u11i*g10r;
        float n11r = u10r*g01r - u10i*g01i + u11r*g11r - u11i*g11i;
        float n11i = u10r*g01i + u10i*g01r + u11r*g11i + u11i*g11r;
        g00r = n00r; g00i = n00i; g01r = n01r; g01i = n01i;
        g10r = n10r; g10i = n10i; g11r = n11r; g11i = n11i;
    }
    int k = (NQ - 1) - q;  // qubit 0 is the MSB of the state index
    __half2* o = reinterpret_cast<__half2*>(gates) + (size_t)k * 8;
    o[0] = __floats2half2_rn(g00r,  g00i);
    o[1] = __floats2half2_rn(-g00i, g00i);
    o[2] = __floats2half2_rn(g01r,  g01i);
    o[3] = __floats2half2_rn(-g01i, g01i);
    o[4] = __floats2half2_rn(g10r,  g10i);
    o[5] = __floats2half2_rn(-g10i, g10i);
    o[6] = __floats2half2_rn(g11r,  g11i);
    o[7] = __floats2half2_rn(-g11i, g11i);
}

__device__ __forceinline__ unsigned h2u(__half2 x) {
    union { __half2 h; unsigned u; } c; c.h = x; return c.u;
}
__device__ __forceinline__ __half2 u2h(unsigned x) {
    union { unsigned u; __half2 h; } c; c.u = x; return c.h;
}
__device__ __forceinline__ __half2 rbroad(float x) {   // (x,x) -> fp16, 1 instr
    union { hv2 a; __half2 b; } c;
    c.a = __builtin_amdgcn_cvt_pkrtz(x, x);
    return c.b;
}

// one complex 2x2 gate on one amp pair (x0,x1) -> (a,b): 8 pk-f16 ops
__device__ __forceinline__ void cbfly(__half2& x0, __half2& x1, const HGate& g) {
    __half2 a = __hmul2(__low2half2(g.m[2]), x1);
    a = __hfma2(g.m[3], __lowhigh2highlow(x1), a);
    a = __hfma2(__low2half2(g.m[0]), x0, a);
    a = __hfma2(g.m[1], __lowhigh2highlow(x0), a);
    __half2 b = __hmul2(__low2half2(g.m[6]), x1);
    b = __hfma2(g.m[7], __lowhigh2highlow(x1), b);
    b = __hfma2(__low2half2(g.m[4]), x0, b);
    b = __hfma2(g.m[5], __lowhigh2highlow(x0), b);
    x0 = a; x1 = b;
}

__device__ __forceinline__ void papplyP(__half2 va[16], __half2 vb[16],
                                        int r0, int r1, const HGate& g) {
    cbfly(va[r0], va[r1], g);
    cbfly(vb[r0], vb[r1], g);
}

__device__ __forceinline__ void papply_rbitP(__half2 va[16], __half2 vb[16],
                                             int rb, const HGate& g) {
    const int m = 1 << rb;
    #pragma unroll
    for (int h = 0; h < 8; ++h) {
        int low = h & (m - 1);
        int r   = ((h & ~(m - 1)) << 1) | low;   // insert 0 at bit rb
        papplyP(va, vb, r, r | m, g);
    }
}

__device__ __forceinline__ unsigned long long packP(__half2 a, __half2 b) {
    return (unsigned long long)h2u(a) | ((unsigned long long)h2u(b) << 32);
}

// XOR keys (see layout derivation in header comment)
#define K1W(r) ( (((r)&1)*17) + ((((r)>>1)&1)*34) + ((((r)>>2)&1)*1024) + ((((r)>>3)&1)*2048) )
#define K1R(r) (r)
#define K2W(r) ((r) << 2)
#define K3R(r) ( (((r)&1)*68) + ((((r)>>1)&1)*136) + ((((r)>>2)&1)*256) + ((((r)>>3)&1)*512) )

__global__ __launch_bounds__(256, 4)
void qc_sim(const float* __restrict__ in,
            const HGate* __restrict__ gp,
            float* __restrict__ out) {
    __shared__ unsigned long long st[DIM];   // 32 KB paired transpose buffer
    __shared__ float red0[4], red1[4];       // per-wave sumsq, per sample

    const int t    = threadIdx.x;
    const int lane = t & 63;
    const int b    = blockIdx.x;             // handles samples 2b, 2b+1

    // ---- issue all global loads first (coalesced float4, 2 rows) ----
    const float4* __restrict__ x40 =
        reinterpret_cast<const float4*>(in + (size_t)(2 * b) * DIM);
    const float4* __restrict__ x41 =
        reinterpret_cast<const float4*>(in + (size_t)(2 * b + 1) * DIM);
    float4 lA[4], lB[4];
    #pragma unroll
    for (int j = 0; j < 4; ++j) lA[j] = x40[j * 256 + t];
    #pragma unroll
    for (int j = 0; j < 4; ++j) lB[j] = x41[j * 256 + t];

    // ---- sum of squares, per-wave reduce (f32), both samples ----
    float s0 = 0.f, s1 = 0.f;
    #pragma unroll
    for (int j = 0; j < 4; ++j) {
        s0 += lA[j].x*lA[j].x + lA[j].y*lA[j].y + lA[j].z*lA[j].z + lA[j].w*lA[j].w;
        s1 += lB[j].x*lB[j].x + lB[j].y*lB[j].y + lB[j].z*lB[j].z + lB[j].w*lB[j].w;
    }
    #pragma unroll
    for (int off = 32; off > 0; off >>= 1) {
        s0 += __shfl_down(s0, off, 64);
        s1 += __shfl_down(s1, off, 64);
    }
    if (lane == 0) { red0[t >> 6] = s0; red1[t >> 6] = s1; }

    // ---- per-thread LDS element bases (8-B element units) ----
    const int T0 = lane & 1, T1 = (lane >> 1) & 1, T2 = (lane >> 2) & 1,
              T3 = (lane >> 3) & 1, T4 = (lane >> 4) & 1, T5 = lane >> 5;
    const int w  = t >> 6;
    const int A1w = T0 | (T1 << 1) | ((T2 ^ T4) << 2) | ((T3 ^ T5) << 3)
                  | (T4 << 6) | (T5 << 7) | (w << 8);
    const int A1r = T0 | (T1 << 1) | (T2 << 2) | (T3 << 3)
                  | (T0 << 4) | (T1 << 5) | (T2 << 6) | (T3 << 7)
                  | (w << 8) | (T4 << 10) | (T5 << 11);
    const int A2w = T0 | (T1 << 1) | (T2 << 2) | (T3 << 3)
                  | (T2 << 6) | (T3 << 7) | (w << 8) | (T4 << 10) | (T5 << 11);
    const int A3  = lane | (w << 10);

    __half2 va[16], vb[16];

    // ---- stage 1 (gates 0,1,10,11); first gate fed from pure-real input ----
    {
        HGate g0 = gp[0];
        #pragma unroll
        for (int j = 0; j < 4; ++j) {
            __half2 p0 = rbroad(lA[j].x), p1 = rbroad(lA[j].y);
            va[4*j]   = __hfma2(g0.m[2], p1, __hmul2(g0.m[0], p0));
            va[4*j+1] = __hfma2(g0.m[6], p1, __hmul2(g0.m[4], p0));
            p0 = rbroad(lA[j].z); p1 = rbroad(lA[j].w);
            va[4*j+2] = __hfma2(g0.m[2], p1, __hmul2(g0.m[0], p0));
            va[4*j+3] = __hfma2(g0.m[6], p1, __hmul2(g0.m[4], p0));
            p0 = rbroad(lB[j].x); p1 = rbroad(lB[j].y);
            vb[4*j]   = __hfma2(g0.m[2], p1, __hmul2(g0.m[0], p0));
            vb[4*j+1] = __hfma2(g0.m[6], p1, __hmul2(g0.m[4], p0));
            p0 = rbroad(lB[j].z); p1 = rbroad(lB[j].w);
            vb[4*j+2] = __hfma2(g0.m[2], p1, __hmul2(g0.m[0], p0));
            vb[4*j+3] = __hfma2(g0.m[6], p1, __hmul2(g0.m[4], p0));
        }
        { HGate g = gp[1];  papply_rbitP(va, vb, 1, g); }
        { HGate g = gp[10]; papply_rbitP(va, vb, 2, g); }
        // last stage-1 gate (reg bit 3): write each finished pair immediately
        { HGate g = gp[11];
          #pragma unroll
          for (int h = 0; h < 8; ++h) {
              papplyP(va, vb, h, h | 8, g);
              st[A1w ^ K1W(h)]     = packP(va[h],     vb[h]);
              st[A1w ^ K1W(h | 8)] = packP(va[h | 8], vb[h | 8]);
          }
        }
    }

    // ---- transpose 1 read: WAVE-LOCAL (elem bits 8,9 = w both sides) ----
    #pragma unroll
    for (int r = 0; r < 16; ++r) {
        unsigned long long u = st[A1r ^ K1R(r)];
        va[r] = u2h((unsigned)u); vb[r] = u2h((unsigned)(u >> 32));
    }

    // ---- stage 2 (gates on idx bits 2..5) ----
    { HGate g = gp[2]; papply_rbitP(va, vb, 0, g); }
    { HGate g = gp[3]; papply_rbitP(va, vb, 1, g); }
    { HGate g = gp[4]; papply_rbitP(va, vb, 2, g); }
    // last stage-2 gate: interleave T2 writes (own-wave region, WAR-safe)
    { HGate g = gp[5];
      #pragma unroll
      for (int h = 0; h < 8; ++h) {
          papplyP(va, vb, h, h | 8, g);
          st[A2w ^ K2W(h)]     = packP(va[h],     vb[h]);
          st[A2w ^ K2W(h | 8)] = packP(va[h | 8], vb[h | 8]);
      }
    }

    __syncthreads();   // the one block barrier (cross-wave read follows)

    #pragma unroll
    for (int r = 0; r < 16; ++r) {
        unsigned long long u = st[A3 ^ K3R(r)];
        va[r] = u2h((unsigned)u); vb[r] = u2h((unsigned)(u >> 32));
    }

    // ---- stage 3 (gates on idx bits 6..9) ----
    { HGate g = gp[6]; papply_rbitP(va, vb, 0, g); }
    { HGate g = gp[7]; papply_rbitP(va, vb, 1, g); }
    { HGate g = gp[8]; papply_rbitP(va, vb, 2, g); }
    { HGate g = gp[9]; papply_rbitP(va, vb, 3, g); }

    // ---- epilogue: prob = |state|^2 / ||x||^2 in f32, coalesced stores ----
    float inv0 = 1.0f / (red0[0] + red0[1] + red0[2] + red0[3]);
    float inv1 = 1.0f / (red1[0] + red1[1] + red1[2] + red1[3]);
    const int sbase = lane | (w << 10);    // map3: idx{0..5}=t0..5, {10,11}=wave
    float* __restrict__ o0 = out + (size_t)(2 * b) * DIM;
    float* __restrict__ o1 = out + (size_t)(2 * b + 1) * DIM;
    #pragma unroll
    for (int r = 0; r < 16; ++r) {
        float re = __low2float(va[r]), im = __high2float(va[r]);
        o0[sbase + (r << 6)] = (re * re + im * im) * inv0;
        re = __low2float(vb[r]); im = __high2float(vb[r]);
        o1[sbase + (r << 6)] = (re * re + im * im) * inv1;
    }
}

extern "C" void kernel_launch(void* const* d_in, const int* in_sizes, int n_in,
                              void* d_out, int out_size, void* d_ws, size_t ws_size,
                              hipStream_t stream) {
    (void)in_sizes; (void)n_in; (void)out_size; (void)ws_size;
    const float* inputs = (const float*)d_in[0];
    const float* thetas = (const float*)d_in[1];
    const float* phis   = (const float*)d_in[2];
    const float* lams   = (const float*)d_in[3];
    float* gates = (float*)d_ws;              // 96 B of scratch (12 x 8 half2)
    float* out   = (float*)d_out;

    hipLaunchKernelGGL(build_gates, dim3(1), dim3(64), 0, stream,
                       thetas, phis, lams, gates);
    hipLaunchKernelGGL(qc_sim, dim3(BATCH / 2), dim3(256), 0, stream,
                       inputs, (const HGate*)gates, out);
}